// Round 7
// baseline (473.345 us; speedup 1.0000x reference)
//
#include <hip/hip_runtime.h>

// Problem constants (n_steps==64 fixed for this instance).
#define BDIM 4096
#define DX 512
#define DZ 512
#define DY 256
#define HD 2048
#define NSTEPS 64
#define LDT 72   // padded LDS row (shorts): 144B stride -> ~2-way (free) on b128
#define NBLK 128 // coop grid (<=256 CUs => co-resident at 1 block/CU)

typedef __attribute__((ext_vector_type(8))) short bf16x8;   // 8 bf16 = 4 VGPRs
typedef __attribute__((ext_vector_type(4))) float f32x4;

__device__ inline unsigned short f2bf(float f) {  // RNE f32 -> bf16
    unsigned u = __float_as_uint(f);
    unsigned r = 0x7FFFu + ((u >> 16) & 1u);
    return (unsigned short)((u + r) >> 16);
}
__device__ inline float bf2f(unsigned short h) {
    return __uint_as_float(((unsigned)h) << 16);
}

// async global->LDS, 16B/lane (used ONLY in the proven gemm_bf16)
#define GLDS16(g, l)                                                            \
    __builtin_amdgcn_global_load_lds((const __attribute__((address_space(1))) void*)(g), \
                                     (__attribute__((address_space(3))) void*)(l), 16, 0, 0)

// ---------------------------------------------------------------------------
// Workspace byte offsets (64B aligned).
constexpr size_t ELS = (size_t)DZ * DZ;  // 262144
constexpr size_t OFF_BAR  = 0;
constexpr size_t OFF_XB   = 64;
constexpr size_t OFF_W2B  = OFF_XB   + (size_t)BDIM * DX * 2;
constexpr size_t OFF_W3B  = OFF_W2B  + (size_t)HD * HD * 2;
constexpr size_t OFF_W1H  = OFF_W3B  + (size_t)DY * HD * 2;
constexpr size_t OFF_W1L  = OFF_W1H  + (size_t)HD * DZ * 2;
constexpr size_t OFF_AH   = OFF_W1L  + (size_t)HD * DZ * 2;
constexpr size_t OFF_AL   = OFF_AH   + ELS * 2;
constexpr size_t OFF_ATH  = OFF_AL   + ELS * 2;
constexpr size_t OFF_ATL  = OFF_ATH  + ELS * 2;
constexpr size_t OFF_PTH  = OFF_ATL  + ELS * 2;
constexpr size_t OFF_PTL  = OFF_PTH  + ELS * 2;
constexpr size_t OFF_M2F  = OFF_PTL  + ELS * 2;
constexpr size_t OFF_M3F  = OFF_M2F  + ELS * 4;
constexpr size_t OFF_M4F  = OFF_M3F  + ELS * 4;
constexpr size_t OFF_M2H  = OFF_M4F  + ELS * 4;
constexpr size_t OFF_M2L  = OFF_M2H  + ELS * 2;
constexpr size_t OFF_M2TH = OFF_M2L  + ELS * 2;
constexpr size_t OFF_M2TL = OFF_M2TH + ELS * 2;
constexpr size_t OFF_SH0  = OFF_M2TL + ELS * 2;
constexpr size_t OFF_SL0  = OFF_SH0  + ELS * 2;
constexpr size_t OFF_STH0 = OFF_SL0  + ELS * 2;
constexpr size_t OFF_STL0 = OFF_STH0 + ELS * 2;
constexpr size_t OFF_SH1  = OFF_STL0 + ELS * 2;
constexpr size_t OFF_SL1  = OFF_SH1  + ELS * 2;
constexpr size_t OFF_STH1 = OFF_SL1  + ELS * 2;
constexpr size_t OFF_STL1 = OFF_STH1 + ELS * 2;
constexpr size_t OFF_RTH  = OFF_STL1 + ELS * 2;
constexpr size_t OFF_RTL  = OFF_RTH  + ELS * 2;
constexpr size_t OFF_C1B  = OFF_RTL  + ELS * 2;
constexpr size_t OFF_H1B  = OFF_C1B  + (size_t)HD * DZ * 2;
constexpr size_t OFF_H2B  = OFF_H1B  + (size_t)BDIM * HD * 2;
// end ~64 MB

// ---------------------------------------------------------------------------
// Batched f32 -> bf16 convert; lo-part optional. Also zeroes the grid barrier.
struct CvtJobs {
    const float* src[5];
    unsigned short* hi[5];
    unsigned short* lo[5];   // null -> hi only
    int n4[5];               // element count / 4
    unsigned* bar;
};
__global__ __launch_bounds__(256) void cvt_multi_k(CvtJobs J) {
    if (blockIdx.x == 0 && blockIdx.y == 0 && threadIdx.x == 0) atomicExch(J.bar, 0u);
    const int j = blockIdx.y;
    const int i4 = blockIdx.x * 256 + threadIdx.x;
    if (i4 >= J.n4[j]) return;
    float4 v = ((const float4*)J.src[j])[i4];
    ushort4 h;
    h.x = f2bf(v.x); h.y = f2bf(v.y); h.z = f2bf(v.z); h.w = f2bf(v.w);
    ((ushort4*)J.hi[j])[i4] = h;
    if (J.lo[j]) {
        ushort4 l;
        l.x = f2bf(v.x - bf2f(h.x));
        l.y = f2bf(v.y - bf2f(h.y));
        l.z = f2bf(v.z - bf2f(h.z));
        l.w = f2bf(v.w - bf2f(h.w));
        ((ushort4*)J.lo[j])[i4] = l;
    }
}

// ---------------------------------------------------------------------------
// Grid barrier: arrive with device-scope add; poll with coherent LOAD (no RMW
// line serialization — round-5's suspected sin) + s_sleep backoff.
__device__ __forceinline__ void gbar(unsigned* bar, unsigned& gen) {
    gen += NBLK;
    __syncthreads();
    if (threadIdx.x == 0) {
        __threadfence();  // release: prior global writes visible device-wide
        __hip_atomic_fetch_add(bar, 1u, __ATOMIC_RELAXED, __HIP_MEMORY_SCOPE_AGENT);
        while (__hip_atomic_load(bar, __ATOMIC_RELAXED, __HIP_MEMORY_SCOPE_AGENT) < gen)
            __builtin_amdgcn_s_sleep(16);
    }
    __syncthreads();
    __threadfence();  // acquire: discard stale cached lines
}

// ---------------------------------------------------------------------------
// Round-6-proven 64x64 NT split GEMM core. C[M,N] = A[M,K] @ B[N,K]^T, hi/lo
// split bf16 inputs (3 MFMAs/pos = fp32-class). BK=64, register prefetch,
// padded LDS (LDT=72). Outputs by nullness.
struct G64In { const unsigned short *Ahi, *Alo, *Bhi, *Blo; };
struct G64Out { float* Cf32; unsigned short *Chi, *Clo, *CThi, *CTlo; };

__device__ __forceinline__ void g64_core(int bx, int by, int M, int N, int K,
                                         G64In in, G64Out o,
                                         unsigned short* Ash, unsigned short* Asl,
                                         unsigned short* Bsh, unsigned short* Bsl) {
    const int tid = threadIdx.x;
    const int lane = tid & 63;
    const int wave = tid >> 6;
    const int wr = wave >> 1, wc = wave & 1;
    const int row0 = by * 64, col0 = bx * 64;
    const int sr = tid >> 2;          // 0..63 stage row
    const int sk = (tid & 3) * 16;    // short offset in 64-short chunk

    const int niter = K >> 6;  // BK=64
    bf16x8 pa0, pa1, pl0, pl1, pb0, pb1, pq0, pq1;
    {
        const unsigned short* ar = in.Ahi + (size_t)(row0 + sr) * K + sk;
        const unsigned short* al = in.Alo + (size_t)(row0 + sr) * K + sk;
        const unsigned short* br = in.Bhi + (size_t)(col0 + sr) * K + sk;
        const unsigned short* bl = in.Blo + (size_t)(col0 + sr) * K + sk;
        pa0 = *(const bf16x8*)ar; pa1 = *(const bf16x8*)(ar + 8);
        pl0 = *(const bf16x8*)al; pl1 = *(const bf16x8*)(al + 8);
        pb0 = *(const bf16x8*)br; pb1 = *(const bf16x8*)(br + 8);
        pq0 = *(const bf16x8*)bl; pq1 = *(const bf16x8*)(bl + 8);
    }

    f32x4 acc[4] = {};
    const int mb = wr * 32 + (lane & 15);
    const int nb = wc * 32 + (lane & 15);

    for (int it = 0; it < niter; ++it) {
        __syncthreads();  // prior LDS consumers done (also covers prior core call)
        *(bf16x8*)&Ash[sr * LDT + sk] = pa0; *(bf16x8*)&Ash[sr * LDT + sk + 8] = pa1;
        *(bf16x8*)&Asl[sr * LDT + sk] = pl0; *(bf16x8*)&Asl[sr * LDT + sk + 8] = pl1;
        *(bf16x8*)&Bsh[sr * LDT + sk] = pb0; *(bf16x8*)&Bsh[sr * LDT + sk + 8] = pb1;
        *(bf16x8*)&Bsl[sr * LDT + sk] = pq0; *(bf16x8*)&Bsl[sr * LDT + sk + 8] = pq1;
        __syncthreads();  // publish

        {   // next-iteration prefetch (latency overlaps MFMA below)
            const int kn = (it + 1 < niter) ? ((it + 1) << 6) : 0;
            const unsigned short* ar = in.Ahi + (size_t)(row0 + sr) * K + kn + sk;
            const unsigned short* al = in.Alo + (size_t)(row0 + sr) * K + kn + sk;
            const unsigned short* br = in.Bhi + (size_t)(col0 + sr) * K + kn + sk;
            const unsigned short* bl = in.Blo + (size_t)(col0 + sr) * K + kn + sk;
            pa0 = *(const bf16x8*)ar; pa1 = *(const bf16x8*)(ar + 8);
            pl0 = *(const bf16x8*)al; pl1 = *(const bf16x8*)(al + 8);
            pb0 = *(const bf16x8*)br; pb1 = *(const bf16x8*)(br + 8);
            pq0 = *(const bf16x8*)bl; pq1 = *(const bf16x8*)(bl + 8);
        }

#pragma unroll
        for (int kh = 0; kh < 2; ++kh) {
            const int kk = kh * 32 + (lane >> 4) * 8;
            bf16x8 ah[2], alx[2], bh[2], blx[2];
#pragma unroll
            for (int t = 0; t < 2; ++t) {
                ah[t]  = *(const bf16x8*)&Ash[(mb + t * 16) * LDT + kk];
                alx[t] = *(const bf16x8*)&Asl[(mb + t * 16) * LDT + kk];
                bh[t]  = *(const bf16x8*)&Bsh[(nb + t * 16) * LDT + kk];
                blx[t] = *(const bf16x8*)&Bsl[(nb + t * 16) * LDT + kk];
            }
#pragma unroll
            for (int mt = 0; mt < 2; ++mt)
#pragma unroll
                for (int nt = 0; nt < 2; ++nt) {
                    acc[mt * 2 + nt] = __builtin_amdgcn_mfma_f32_16x16x32_bf16(
                        ah[mt], bh[nt], acc[mt * 2 + nt], 0, 0, 0);
                    acc[mt * 2 + nt] = __builtin_amdgcn_mfma_f32_16x16x32_bf16(
                        ah[mt], blx[nt], acc[mt * 2 + nt], 0, 0, 0);
                    acc[mt * 2 + nt] = __builtin_amdgcn_mfma_f32_16x16x32_bf16(
                        alx[mt], bh[nt], acc[mt * 2 + nt], 0, 0, 0);
                }
        }
    }

    // epilogue — C/D layout: col=lane&15, row=(lane>>4)*4+reg
#pragma unroll
    for (int mt = 0; mt < 2; ++mt) {
        const int grow = row0 + wr * 32 + mt * 16 + (lane >> 4) * 4;
#pragma unroll
        for (int nt = 0; nt < 2; ++nt) {
            const int gcol = col0 + wc * 32 + nt * 16 + (lane & 15);
            f32x4 a = acc[mt * 2 + nt];
            unsigned short h4[4], l4[4];
#pragma unroll
            for (int i = 0; i < 4; ++i) {
                h4[i] = f2bf(a[i]);
                l4[i] = f2bf(a[i] - bf2f(h4[i]));
            }
            if (o.Cf32) {
#pragma unroll
                for (int i = 0; i < 4; ++i) o.Cf32[(size_t)(grow + i) * N + gcol] = a[i];
            }
            if (o.Chi) {
#pragma unroll
                for (int i = 0; i < 4; ++i) o.Chi[(size_t)(grow + i) * N + gcol] = h4[i];
            }
            if (o.Clo) {
#pragma unroll
                for (int i = 0; i < 4; ++i) o.Clo[(size_t)(grow + i) * N + gcol] = l4[i];
            }
            if (o.CThi) {
                ushort4 u = {h4[0], h4[1], h4[2], h4[3]};
                *(ushort4*)&o.CThi[(size_t)gcol * M + grow] = u;
            }
            if (o.CTlo) {
                ushort4 u = {l4[0], l4[1], l4[2], l4[3]};
                *(ushort4*)&o.CTlo[(size_t)gcol * M + grow] = u;
            }
        }
    }
}

// ---------------------------------------------------------------------------
// Whole 512-chain in ONE launch (128 blocks): transposed splits -> M2 ->
// {M3||M4} -> taylor(+T) -> 6 squarings -> R -> C1. Round-6 core per phase.
__global__ __launch_bounds__(256, 1) void chain_coop(const float* __restrict__ Am,
                                                     const float* __restrict__ P, char* ws) {
    __shared__ __align__(16) unsigned short Ash[64 * LDT];
    __shared__ __align__(16) unsigned short Asl[64 * LDT];
    __shared__ __align__(16) unsigned short Bsh[64 * LDT];
    __shared__ __align__(16) unsigned short Bsl[64 * LDT];

    unsigned* bar = (unsigned*)(ws + OFF_BAR);
    unsigned short* Ah   = (unsigned short*)(ws + OFF_AH);
    unsigned short* Al_  = (unsigned short*)(ws + OFF_AL);
    unsigned short* ATh  = (unsigned short*)(ws + OFF_ATH);
    unsigned short* ATl  = (unsigned short*)(ws + OFF_ATL);
    unsigned short* PTh  = (unsigned short*)(ws + OFF_PTH);
    unsigned short* PTl  = (unsigned short*)(ws + OFF_PTL);
    float* M2f = (float*)(ws + OFF_M2F);
    float* M3f = (float*)(ws + OFF_M3F);
    float* M4f = (float*)(ws + OFF_M4F);
    unsigned short* M2h  = (unsigned short*)(ws + OFF_M2H);
    unsigned short* M2l  = (unsigned short*)(ws + OFF_M2L);
    unsigned short* M2Th = (unsigned short*)(ws + OFF_M2TH);
    unsigned short* M2Tl = (unsigned short*)(ws + OFF_M2TL);
    unsigned short* Shb[2]  = {(unsigned short*)(ws + OFF_SH0),  (unsigned short*)(ws + OFF_SH1)};
    unsigned short* Slb[2]  = {(unsigned short*)(ws + OFF_SL0),  (unsigned short*)(ws + OFF_SL1)};
    unsigned short* SThb[2] = {(unsigned short*)(ws + OFF_STH0), (unsigned short*)(ws + OFF_STH1)};
    unsigned short* STlb[2] = {(unsigned short*)(ws + OFF_STL0), (unsigned short*)(ws + OFF_STL1)};
    unsigned short* RTh  = (unsigned short*)(ws + OFF_RTH);
    unsigned short* RTl  = (unsigned short*)(ws + OFF_RTL);
    unsigned short* W1h  = (unsigned short*)(ws + OFF_W1H);
    unsigned short* W1l  = (unsigned short*)(ws + OFF_W1L);
    unsigned short* C1b  = (unsigned short*)(ws + OFF_C1B);

    unsigned gen = 0;
    const int blk = blockIdx.x;
    const int x = threadIdx.x & 31, y8 = threadIdx.x >> 5;  // 32x8 view
    float (*tls)[33] = (float(*)[33])(void*)Ash;            // 4224B < 9216B

    // Ph A: transposed splits of A and P: 512 tiles of 32x32, 4/block
#pragma unroll 1
    for (int j = 0; j < 4; ++j) {
        const int q = blk * 4 + j;
        const float* src = (q < 256) ? Am : P;
        unsigned short* HT = (q < 256) ? ATh : PTh;
        unsigned short* LT = (q < 256) ? ATl : PTl;
        const int r = q & 255;
        const int bx = (r & 15) * 32, by = (r >> 4) * 32;
        __syncthreads();
#pragma unroll
        for (int dy = 0; dy < 32; dy += 8)
            tls[y8 + dy][x] = src[(size_t)(by + y8 + dy) * DZ + bx + x];
        __syncthreads();
#pragma unroll
        for (int dy = 0; dy < 32; dy += 8) {
            float v = tls[x][y8 + dy];
            unsigned short h = f2bf(v);
            size_t o = (size_t)(bx + y8 + dy) * DZ + by + x;
            HT[o] = h;
            LT[o] = f2bf(v - bf2f(h));
        }
    }
    gbar(bar, gen);

    // Ph B: M2 = A@A : NT(A, AT) -> f32 + split + splitT (64 tiles)
    if (blk < 64) {
        G64In i{Ah, Al_, ATh, ATl};
        G64Out o{M2f, M2h, M2l, M2Th, M2Tl};
        g64_core(blk & 7, blk >> 3, DZ, DZ, DZ, i, o, Ash, Asl, Bsh, Bsl);
    }
    gbar(bar, gen);

    // Ph C: M3 = M2@A -> f32 ; M4 = M2@M2 -> f32 (128 tiles, full grid)
    {
        G64In i = (blk < 64) ? G64In{M2h, M2l, ATh, ATl} : G64In{M2h, M2l, M2Th, M2Tl};
        G64Out o{(blk < 64) ? M3f : M4f, nullptr, nullptr, nullptr, nullptr};
        const int t = blk & 63;
        g64_core(t & 7, t >> 3, DZ, DZ, DZ, i, o, Ash, Asl, Bsh, Bsl);
    }
    gbar(bar, gen);

    // Ph D: S = I + h*A + c2*M2 + c3*M3 + c4*M4, split + splitT (256 tiles, 2/block)
    {
        const float hh = 1.0f / (float)NSTEPS;
        const float c2 = 0.5f * hh * hh;
        const float c3 = hh * hh * hh * (1.0f / 6.0f);
        const float c4 = hh * hh * hh * hh * (1.0f / 24.0f);
#pragma unroll 1
        for (int j = 0; j < 2; ++j) {
            const int r = blk * 2 + j;
            const int bx = (r & 15) * 32, by = (r >> 4) * 32;
            __syncthreads();
#pragma unroll
            for (int dy = 0; dy < 32; dy += 8) {
                const int row = by + y8 + dy, col = bx + x;
                const size_t idx = (size_t)row * DZ + col;
                float s = hh * Am[idx] + c2 * M2f[idx] + c3 * M3f[idx] + c4 * M4f[idx];
                if (row == col) s += 1.0f;
                tls[y8 + dy][x] = s;
                unsigned short hi = f2bf(s);
                Shb[0][idx] = hi;
                Slb[0][idx] = f2bf(s - bf2f(hi));
            }
            __syncthreads();
#pragma unroll
            for (int dy = 0; dy < 32; dy += 8) {
                float s = tls[x][y8 + dy];
                size_t o = (size_t)(bx + y8 + dy) * DZ + by + x;
                unsigned short hi = f2bf(s);
                SThb[0][o] = hi;
                STlb[0][o] = f2bf(s - bf2f(hi));
            }
        }
    }
    gbar(bar, gen);

    // Ph E: Q = S^64 via 6 squarings (64 tiles each)
    int cur = 0;
#pragma unroll 1
    for (int s = 0; s < 6; ++s) {
        if (blk < 64) {
            G64In i{Shb[cur], Slb[cur], SThb[cur], STlb[cur]};
            G64Out o{nullptr, Shb[1 - cur], Slb[1 - cur], SThb[1 - cur], STlb[1 - cur]};
            g64_core(blk & 7, blk >> 3, DZ, DZ, DZ, i, o, Ash, Asl, Bsh, Bsl);
        }
        gbar(bar, gen);
        cur ^= 1;
    }

    // Ph F: R = Q@P : NT(Q, PT) -> R^T split only (64 tiles)
    if (blk < 64) {
        G64In i{Shb[cur], Slb[cur], PTh, PTl};
        G64Out o{nullptr, nullptr, nullptr, RTh, RTl};
        g64_core(blk & 7, blk >> 3, DZ, DZ, DZ, i, o, Ash, Asl, Bsh, Bsl);
    }
    gbar(bar, gen);

    // Ph G: C1 = W1@R : NT(W1, RT) -> hi row-major [HD, DZ] (256 tiles, 2/block)
#pragma unroll 1
    for (int j = 0; j < 2; ++j) {
        const int t = blk + j * NBLK;
        G64In i{W1h, W1l, RTh, RTl};
        G64Out o{nullptr, C1b, nullptr, nullptr, nullptr};
        g64_core(t & 7, t >> 3, HD, DZ, DZ, i, o, Ash, Asl, Bsh, Bsl);
    }
}

// ---------------------------------------------------------------------------
// Big bf16 MFMA GEMM (proven): C[M,N] = A[M,K] @ B[N,K]^T (+bias)(relu)
// 128x128 tile, BK=32, 4 waves 2x2 (each 64x64).
template <int RELU, int BIAS, int OUT_BF16>
__global__ __launch_bounds__(256) void gemm_bf16(int M, int N, int K,
                                                 const unsigned short* __restrict__ A,
                                                 const unsigned short* __restrict__ B,
                                                 void* __restrict__ C,
                                                 const float* __restrict__ bias) {
    __shared__ unsigned short As[128 * 32];
    __shared__ unsigned short Bs[128 * 32];

    const int tid = threadIdx.x;
    const int lane = tid & 63;
    const int wave = tid >> 6;
    const int wr = wave >> 1, wc = wave & 1;
    const int row0 = blockIdx.y * 128;
    const int col0 = blockIdx.x * 128;

    const int srow = lane >> 2;
    const int schunk = (lane & 3) * 8;

    f32x4 acc[4][4] = {};

    for (int k0 = 0; k0 < K; k0 += 32) {
        const int r0 = wave * 32;
        GLDS16(A + (size_t)(row0 + r0 + srow) * K + k0 + schunk, &As[r0 * 32]);
        GLDS16(A + (size_t)(row0 + r0 + 16 + srow) * K + k0 + schunk, &As[(r0 + 16) * 32]);
        GLDS16(B + (size_t)(col0 + r0 + srow) * K + k0 + schunk, &Bs[r0 * 32]);
        GLDS16(B + (size_t)(col0 + r0 + 16 + srow) * K + k0 + schunk, &Bs[(r0 + 16) * 32]);
        __syncthreads();

        const int kk = (lane >> 4) * 8;
        const int mbase = wr * 64 + (lane & 15);
        const int nbase = wc * 64 + (lane & 15);
        bf16x8 af[4], bf[4];
#pragma unroll
        for (int t = 0; t < 4; ++t) {
            af[t] = *(const bf16x8*)&As[(mbase + t * 16) * 32 + kk];
            bf[t] = *(const bf16x8*)&Bs[(nbase + t * 16) * 32 + kk];
        }
#pragma unroll
        for (int mt = 0; mt < 4; ++mt)
#pragma unroll
            for (int nt = 0; nt < 4; ++nt)
                acc[mt][nt] = __builtin_amdgcn_mfma_f32_16x16x32_bf16(af[mt], bf[nt],
                                                                      acc[mt][nt], 0, 0, 0);
        __syncthreads();
    }

#pragma unroll
    for (int mt = 0; mt < 4; ++mt) {
        const int grow = row0 + wr * 64 + mt * 16 + (lane >> 4) * 4;
#pragma unroll
        for (int nt = 0; nt < 4; ++nt) {
            const int gcol = col0 + wc * 64 + nt * 16 + (lane & 15);
            const float bv = BIAS ? bias[gcol] : 0.0f;
#pragma unroll
            for (int i = 0; i < 4; ++i) {
                float v = acc[mt][nt][i] + bv;
                if (RELU) v = fmaxf(v, 0.0f);
                const size_t off = (size_t)(grow + i) * N + gcol;
                if (OUT_BF16)
                    ((unsigned short*)C)[off] = f2bf(v);
                else
                    ((float*)C)[off] = v;
            }
        }
    }
}

// ---------------------------------------------------------------------------
// y-GEMM: 64x64 NT bf16, BK=64 + register prefetch + padded LDS, fp32 out+bias.
__global__ __launch_bounds__(256) void gemm64nt_y(int M, int N, int K,
                                                  const unsigned short* __restrict__ A,
                                                  const unsigned short* __restrict__ B,
                                                  float* __restrict__ C,
                                                  const float* __restrict__ bias) {
    __shared__ __align__(16) unsigned short As[64 * LDT];
    __shared__ __align__(16) unsigned short Bs[64 * LDT];
    const int tid = threadIdx.x;
    const int lane = tid & 63;
    const int wave = tid >> 6;
    const int wr = wave >> 1, wc = wave & 1;
    const int row0 = blockIdx.y * 64;
    const int col0 = blockIdx.x * 64;
    const int sr = tid >> 2, sk = (tid & 3) * 16;

    const int niter = K >> 6;
    bf16x8 pa0, pa1, pb0, pb1;
    {
        const unsigned short* ar = A + (size_t)(row0 + sr) * K + sk;
        const unsigned short* br = B + (size_t)(col0 + sr) * K + sk;
        pa0 = *(const bf16x8*)ar; pa1 = *(const bf16x8*)(ar + 8);
        pb0 = *(const bf16x8*)br; pb1 = *(const bf16x8*)(br + 8);
    }

    f32x4 acc[4] = {};
    const int mb = wr * 32 + (lane & 15);
    const int nb = wc * 32 + (lane & 15);

    for (int it = 0; it < niter; ++it) {
        __syncthreads();
        *(bf16x8*)&As[sr * LDT + sk] = pa0; *(bf16x8*)&As[sr * LDT + sk + 8] = pa1;
        *(bf16x8*)&Bs[sr * LDT + sk] = pb0; *(bf16x8*)&Bs[sr * LDT + sk + 8] = pb1;
        __syncthreads();

        {
            const int kn = (it + 1 < niter) ? ((it + 1) << 6) : 0;
            const unsigned short* ar = A + (size_t)(row0 + sr) * K + kn + sk;
            const unsigned short* br = B + (size_t)(col0 + sr) * K + kn + sk;
            pa0 = *(const bf16x8*)ar; pa1 = *(const bf16x8*)(ar + 8);
            pb0 = *(const bf16x8*)br; pb1 = *(const bf16x8*)(br + 8);
        }

#pragma unroll
        for (int kh = 0; kh < 2; ++kh) {
            const int kk = kh * 32 + (lane >> 4) * 8;
            bf16x8 af[2], bf[2];
#pragma unroll
            for (int t = 0; t < 2; ++t) {
                af[t] = *(const bf16x8*)&As[(mb + t * 16) * LDT + kk];
                bf[t] = *(const bf16x8*)&Bs[(nb + t * 16) * LDT + kk];
            }
#pragma unroll
            for (int mt = 0; mt < 2; ++mt)
#pragma unroll
                for (int nt = 0; nt < 2; ++nt)
                    acc[mt * 2 + nt] = __builtin_amdgcn_mfma_f32_16x16x32_bf16(
                        af[mt], bf[nt], acc[mt * 2 + nt], 0, 0, 0);
        }
    }

#pragma unroll
    for (int mt = 0; mt < 2; ++mt) {
        const int grow = row0 + wr * 32 + mt * 16 + (lane >> 4) * 4;
#pragma unroll
        for (int nt = 0; nt < 2; ++nt) {
            const int gcol = col0 + wc * 32 + nt * 16 + (lane & 15);
            const float bv = bias ? bias[gcol] : 0.0f;
#pragma unroll
            for (int i = 0; i < 4; ++i)
                C[(size_t)(grow + i) * N + gcol] = acc[mt * 2 + nt][i] + bv;
        }
    }
}

// ---------------------------------------------------------------------------
extern "C" void kernel_launch(void* const* d_in, const int* in_sizes, int n_in,
                              void* d_out, int out_size, void* d_ws, size_t ws_size,
                              hipStream_t stream) {
    const float* X  = (const float*)d_in[0];  // [B, Dx]
    const float* P  = (const float*)d_in[1];  // [Dz, Dx]
    const float* Am = (const float*)d_in[2];  // [Dz, Dz]
    const float* W1 = (const float*)d_in[3];  // [H, Dz]
    const float* b1 = (const float*)d_in[4];
    const float* W2 = (const float*)d_in[5];  // [H, H]
    const float* b2 = (const float*)d_in[6];
    const float* W3 = (const float*)d_in[7];  // [Dy, H]
    const float* b3 = (const float*)d_in[8];
    float* out = (float*)d_out;               // [B, Dy] fp32

    char* ws = (char*)d_ws;
    unsigned short* Xb  = (unsigned short*)(ws + OFF_XB);
    unsigned short* W2b = (unsigned short*)(ws + OFF_W2B);
    unsigned short* W3b = (unsigned short*)(ws + OFF_W3B);
    unsigned short* W1h = (unsigned short*)(ws + OFF_W1H);
    unsigned short* W1l = (unsigned short*)(ws + OFF_W1L);
    unsigned short* Ah  = (unsigned short*)(ws + OFF_AH);
    unsigned short* Al  = (unsigned short*)(ws + OFF_AL);
    unsigned short* C1b = (unsigned short*)(ws + OFF_C1B);
    unsigned short* h1b = (unsigned short*)(ws + OFF_H1B);
    unsigned short* h2b = (unsigned short*)(ws + OFF_H2B);

    // ---- L1: converts/splits + barrier zero ----
    CvtJobs J;
    J.src[0] = X;  J.hi[0] = Xb;  J.lo[0] = nullptr; J.n4[0] = BDIM * DX / 4;
    J.src[1] = W2; J.hi[1] = W2b; J.lo[1] = nullptr; J.n4[1] = HD * HD / 4;
    J.src[2] = W3; J.hi[2] = W3b; J.lo[2] = nullptr; J.n4[2] = DY * HD / 4;
    J.src[3] = W1; J.hi[3] = W1h; J.lo[3] = W1l;     J.n4[3] = HD * DZ / 4;
    J.src[4] = Am; J.hi[4] = Ah;  J.lo[4] = Al;      J.n4[4] = (int)(ELS / 4);
    J.bar = (unsigned*)(ws + OFF_BAR);
    cvt_multi_k<<<dim3(HD * HD / 4 / 256, 5), 256, 0, stream>>>(J);

    // ---- L2: entire 512-chain in one cooperative launch ----
    chain_coop<<<dim3(NBLK), 256, 0, stream>>>(Am, P, ws);

    // ---- L3: h1 = relu(X @ C1^T + b1) ----
    gemm_bf16<1, 1, 1><<<dim3(HD / 128, BDIM / 128), 256, 0, stream>>>(
        BDIM, HD, DX, Xb, C1b, h1b, b1);
    // ---- L4: h2 = relu(h1 @ W2^T + b2) ----
    gemm_bf16<1, 1, 1><<<dim3(HD / 128, BDIM / 128), 256, 0, stream>>>(
        BDIM, HD, HD, h1b, W2b, h2b, b2);
    // ---- L5: y = h2 @ W3^T + b3 (fp32 out) ----
    gemm64nt_y<<<dim3(DY / 64, BDIM / 64), 256, 0, stream>>>(
        BDIM, DY, HD, h2b, W3b, out, b3);
}

// Round 8
// 267.286 us; speedup vs baseline: 1.7709x; 1.7709x over previous
//
#include <hip/hip_runtime.h>

// Problem constants (n_steps==64 fixed for this instance).
#define BDIM 4096
#define DX 512
#define DZ 512
#define DY 256
#define HD 2048
#define LDT 72   // padded LDS row (shorts): 144B stride, ~2-way (free) on b128

typedef __attribute__((ext_vector_type(8))) short bf16x8;   // 8 bf16 = 4 VGPRs
typedef __attribute__((ext_vector_type(4))) float f32x4;

__device__ inline unsigned short f2bf(float f) {  // RNE f32 -> bf16
    unsigned u = __float_as_uint(f);
    unsigned r = 0x7FFFu + ((u >> 16) & 1u);
    return (unsigned short)((u + r) >> 16);
}
__device__ inline float bf2f(unsigned short h) {
    return __uint_as_float(((unsigned)h) << 16);
}

// async global->LDS, 16B/lane (proven pattern: wave-uniform base + lane*16)
#define GLDS16(g, l)                                                            \
    __builtin_amdgcn_global_load_lds((const __attribute__((address_space(1))) void*)(g), \
                                     (__attribute__((address_space(3))) void*)(l), 16, 0, 0)

// ---------------------------------------------------------------------------
// Batched f32 -> bf16 convert; lo-part optional (hi/lo split).
struct CvtJobs {
    const float* src[5];
    unsigned short* hi[5];
    unsigned short* lo[5];   // null -> hi only
    int n4[5];               // element count / 4
};
__global__ __launch_bounds__(256) void cvt_multi_k(CvtJobs J) {
    const int j = blockIdx.y;
    const int i4 = blockIdx.x * 256 + threadIdx.x;
    if (i4 >= J.n4[j]) return;
    float4 v = ((const float4*)J.src[j])[i4];
    ushort4 h;
    h.x = f2bf(v.x); h.y = f2bf(v.y); h.z = f2bf(v.z); h.w = f2bf(v.w);
    ((ushort4*)J.hi[j])[i4] = h;
    if (J.lo[j]) {
        ushort4 l;
        l.x = f2bf(v.x - bf2f(h.x));
        l.y = f2bf(v.y - bf2f(h.y));
        l.z = f2bf(v.z - bf2f(h.z));
        l.w = f2bf(v.w - bf2f(h.w));
        ((ushort4*)J.lo[j])[i4] = l;
    }
}

// ---------------------------------------------------------------------------
// Transposed split: HT/LT[j*D+i] = split(A[i*D+j]). z-batched over 2 matrices.
__global__ __launch_bounds__(256) void split_t_k(const float* __restrict__ A0,
                                                 unsigned short* __restrict__ H0,
                                                 unsigned short* __restrict__ L0,
                                                 const float* __restrict__ A1,
                                                 unsigned short* __restrict__ H1,
                                                 unsigned short* __restrict__ L1, int D) {
    const float* A = blockIdx.z ? A1 : A0;
    unsigned short* HT = blockIdx.z ? H1 : H0;
    unsigned short* LT = blockIdx.z ? L1 : L0;
    __shared__ float t[32][33];
    const int bx = blockIdx.x * 32, by = blockIdx.y * 32;
    const int x = threadIdx.x, y = threadIdx.y;  // block (32,8)
#pragma unroll
    for (int dy = 0; dy < 32; dy += 8)
        t[y + dy][x] = A[(size_t)(by + y + dy) * D + bx + x];
    __syncthreads();
#pragma unroll
    for (int dy = 0; dy < 32; dy += 8) {
        float v = t[x][y + dy];
        unsigned short h = f2bf(v);
        size_t o = (size_t)(bx + y + dy) * D + by + x;
        HT[o] = h;
        LT[o] = f2bf(v - bf2f(h));
    }
}

// ---------------------------------------------------------------------------
// E0: Paterson-Stockmeyer groups for degree-15 Taylor of exp(A):
//   B_q = c[4q]*I + c[4q+1]*A + c[4q+2]*A2 + c[4q+3]*A3, q=0..3 (c_k = 1/k!)
// Outputs: B0,B1,B2 f32 (Horner D-addends); B3 split hi/lo (Horner A-operand).
__global__ __launch_bounds__(256) void e0_k(const float* __restrict__ A,
                                            const float* __restrict__ A2,
                                            const float* __restrict__ A3,
                                            float* __restrict__ B0,
                                            float* __restrict__ B1,
                                            float* __restrict__ B2,
                                            unsigned short* __restrict__ B3h,
                                            unsigned short* __restrict__ B3l) {
    const int i4 = blockIdx.x * 256 + threadIdx.x;   // 65536 total
    const int base = i4 * 4;
    const int row = base >> 9, col = base & 511;
    const int d = row - col;  // j==d -> diagonal element
    float4 a = ((const float4*)A)[i4];
    float4 a2 = ((const float4*)A2)[i4];
    float4 a3 = ((const float4*)A3)[i4];
    float av[4] = {a.x, a.y, a.z, a.w};
    float a2v[4] = {a2.x, a2.y, a2.z, a2.w};
    float a3v[4] = {a3.x, a3.y, a3.z, a3.w};
    float b0[4], b1[4], b2[4];
    ushort4 h3, l3;
    unsigned short* h3p = &h3.x;
    unsigned short* l3p = &l3.x;
#pragma unroll
    for (int j = 0; j < 4; ++j) {
        const float di = (j == d) ? 1.0f : 0.0f;
        b0[j] = di + av[j] + 0.5f * a2v[j] + 1.6666667e-1f * a3v[j];
        b1[j] = 4.1666668e-2f * di + 8.3333333e-3f * av[j] +
                1.3888889e-3f * a2v[j] + 1.9841270e-4f * a3v[j];
        b2[j] = 2.4801587e-5f * di + 2.7557319e-6f * av[j] +
                2.7557319e-7f * a2v[j] + 2.5052108e-8f * a3v[j];
        float b3 = 2.0876757e-9f * di + 1.6059044e-10f * av[j] +
                   1.1470746e-11f * a2v[j] + 7.6471637e-13f * a3v[j];
        unsigned short hh = f2bf(b3);
        h3p[j] = hh;
        l3p[j] = f2bf(b3 - bf2f(hh));
    }
    ((float4*)B0)[i4] = make_float4(b0[0], b0[1], b0[2], b0[3]);
    ((float4*)B1)[i4] = make_float4(b1[0], b1[1], b1[2], b1[3]);
    ((float4*)B2)[i4] = make_float4(b2[0], b2[1], b2[2], b2[3]);
    ((ushort4*)B3h)[i4] = h3;
    ((ushort4*)B3l)[i4] = l3;
}

// ---------------------------------------------------------------------------
// Round-6-proven 64x64 NT split GEMM core: C = A @ B^T (+D), hi/lo split bf16
// inputs (3 MFMAs/pos = fp32-class). BK=64, register prefetch, padded LDS.
// NEW: optional f32 addend D (epilogue). Outputs by nullness.
struct G64In { const unsigned short *Ahi, *Alo, *Bhi, *Blo; const float* Dadd; };
struct G64Out { float* Cf32; unsigned short *Chi, *Clo, *CThi, *CTlo; };

__device__ __forceinline__ void g64_core(int bx, int by, int M, int N, int K,
                                         G64In in, G64Out o,
                                         unsigned short* Ash, unsigned short* Asl,
                                         unsigned short* Bsh, unsigned short* Bsl) {
    const int tid = threadIdx.x;
    const int lane = tid & 63;
    const int wave = tid >> 6;
    const int wr = wave >> 1, wc = wave & 1;
    const int row0 = by * 64, col0 = bx * 64;
    const int sr = tid >> 2;          // 0..63 stage row
    const int sk = (tid & 3) * 16;    // short offset in 64-short chunk

    const int niter = K >> 6;  // BK=64
    bf16x8 pa0, pa1, pl0, pl1, pb0, pb1, pq0, pq1;
    {
        const unsigned short* ar = in.Ahi + (size_t)(row0 + sr) * K + sk;
        const unsigned short* al = in.Alo + (size_t)(row0 + sr) * K + sk;
        const unsigned short* br = in.Bhi + (size_t)(col0 + sr) * K + sk;
        const unsigned short* bl = in.Blo + (size_t)(col0 + sr) * K + sk;
        pa0 = *(const bf16x8*)ar; pa1 = *(const bf16x8*)(ar + 8);
        pl0 = *(const bf16x8*)al; pl1 = *(const bf16x8*)(al + 8);
        pb0 = *(const bf16x8*)br; pb1 = *(const bf16x8*)(br + 8);
        pq0 = *(const bf16x8*)bl; pq1 = *(const bf16x8*)(bl + 8);
    }

    f32x4 acc[4] = {};
    const int mb = wr * 32 + (lane & 15);
    const int nb = wc * 32 + (lane & 15);

    for (int it = 0; it < niter; ++it) {
        __syncthreads();
        *(bf16x8*)&Ash[sr * LDT + sk] = pa0; *(bf16x8*)&Ash[sr * LDT + sk + 8] = pa1;
        *(bf16x8*)&Asl[sr * LDT + sk] = pl0; *(bf16x8*)&Asl[sr * LDT + sk + 8] = pl1;
        *(bf16x8*)&Bsh[sr * LDT + sk] = pb0; *(bf16x8*)&Bsh[sr * LDT + sk + 8] = pb1;
        *(bf16x8*)&Bsl[sr * LDT + sk] = pq0; *(bf16x8*)&Bsl[sr * LDT + sk + 8] = pq1;
        __syncthreads();

        {   // next-iteration prefetch (latency overlaps MFMA below)
            const int kn = (it + 1 < niter) ? ((it + 1) << 6) : 0;
            const unsigned short* ar = in.Ahi + (size_t)(row0 + sr) * K + kn + sk;
            const unsigned short* al = in.Alo + (size_t)(row0 + sr) * K + kn + sk;
            const unsigned short* br = in.Bhi + (size_t)(col0 + sr) * K + kn + sk;
            const unsigned short* bl = in.Blo + (size_t)(col0 + sr) * K + kn + sk;
            pa0 = *(const bf16x8*)ar; pa1 = *(const bf16x8*)(ar + 8);
            pl0 = *(const bf16x8*)al; pl1 = *(const bf16x8*)(al + 8);
            pb0 = *(const bf16x8*)br; pb1 = *(const bf16x8*)(br + 8);
            pq0 = *(const bf16x8*)bl; pq1 = *(const bf16x8*)(bl + 8);
        }

#pragma unroll
        for (int kh = 0; kh < 2; ++kh) {
            const int kk = kh * 32 + (lane >> 4) * 8;
            bf16x8 ah[2], alx[2], bh[2], blx[2];
#pragma unroll
            for (int t = 0; t < 2; ++t) {
                ah[t]  = *(const bf16x8*)&Ash[(mb + t * 16) * LDT + kk];
                alx[t] = *(const bf16x8*)&Asl[(mb + t * 16) * LDT + kk];
                bh[t]  = *(const bf16x8*)&Bsh[(nb + t * 16) * LDT + kk];
                blx[t] = *(const bf16x8*)&Bsl[(nb + t * 16) * LDT + kk];
            }
#pragma unroll
            for (int mt = 0; mt < 2; ++mt)
#pragma unroll
                for (int nt = 0; nt < 2; ++nt) {
                    acc[mt * 2 + nt] = __builtin_amdgcn_mfma_f32_16x16x32_bf16(
                        ah[mt], bh[nt], acc[mt * 2 + nt], 0, 0, 0);
                    acc[mt * 2 + nt] = __builtin_amdgcn_mfma_f32_16x16x32_bf16(
                        ah[mt], blx[nt], acc[mt * 2 + nt], 0, 0, 0);
                    acc[mt * 2 + nt] = __builtin_amdgcn_mfma_f32_16x16x32_bf16(
                        alx[mt], bh[nt], acc[mt * 2 + nt], 0, 0, 0);
                }
        }
    }

    // epilogue — C/D layout: col=lane&15, row=(lane>>4)*4+reg
#pragma unroll
    for (int mt = 0; mt < 2; ++mt) {
        const int grow = row0 + wr * 32 + mt * 16 + (lane >> 4) * 4;
#pragma unroll
        for (int nt = 0; nt < 2; ++nt) {
            const int gcol = col0 + wc * 32 + nt * 16 + (lane & 15);
            f32x4 a = acc[mt * 2 + nt];
            if (in.Dadd) {
#pragma unroll
                for (int i = 0; i < 4; ++i)
                    a[i] += in.Dadd[(size_t)(grow + i) * N + gcol];
            }
            unsigned short h4[4], l4[4];
#pragma unroll
            for (int i = 0; i < 4; ++i) {
                h4[i] = f2bf(a[i]);
                l4[i] = f2bf(a[i] - bf2f(h4[i]));
            }
            if (o.Cf32) {
#pragma unroll
                for (int i = 0; i < 4; ++i) o.Cf32[(size_t)(grow + i) * N + gcol] = a[i];
            }
            if (o.Chi) {
#pragma unroll
                for (int i = 0; i < 4; ++i) o.Chi[(size_t)(grow + i) * N + gcol] = h4[i];
            }
            if (o.Clo) {
#pragma unroll
                for (int i = 0; i < 4; ++i) o.Clo[(size_t)(grow + i) * N + gcol] = l4[i];
            }
            if (o.CThi) {
                ushort4 u = {h4[0], h4[1], h4[2], h4[3]};
                *(ushort4*)&o.CThi[(size_t)gcol * M + grow] = u;
            }
            if (o.CTlo) {
                ushort4 u = {l4[0], l4[1], l4[2], l4[3]};
                *(ushort4*)&o.CTlo[(size_t)gcol * M + grow] = u;
            }
        }
    }
}

__global__ __launch_bounds__(256) void g64_one(G64In in, G64Out o, int M, int N, int K) {
    __shared__ __align__(16) unsigned short Ash[64 * LDT], Asl[64 * LDT];
    __shared__ __align__(16) unsigned short Bsh[64 * LDT], Bsl[64 * LDT];
    g64_core(blockIdx.x, blockIdx.y, M, N, K, in, o, Ash, Asl, Bsh, Bsl);
}

__global__ __launch_bounds__(256) void g64_dual(G64In i0, G64Out o0, G64In i1, G64Out o1,
                                                int M, int N, int K) {
    __shared__ __align__(16) unsigned short Ash[64 * LDT], Asl[64 * LDT];
    __shared__ __align__(16) unsigned short Bsh[64 * LDT], Bsl[64 * LDT];
    g64_core(blockIdx.x, blockIdx.y, M, N, K, blockIdx.z ? i1 : i0, blockIdx.z ? o1 : o0,
             Ash, Asl, Bsh, Bsl);
}

// ---------------------------------------------------------------------------
// Big bf16 MFMA GEMM v2: 64(M)x128(N) tile -> 2x the blocks of the 128x128
// version (grid-limited occupancy fix). C = A @ B^T (+bias)(relu).
// BK=32, 4 waves 2x2 (each 32x64 = 2x4 MFMAs). GLDS16 staging (proven pattern).
template <int RELU, int BIAS, int OUT_BF16>
__global__ __launch_bounds__(256) void gemm_bf16_v2(int M, int N, int K,
                                                    const unsigned short* __restrict__ A,
                                                    const unsigned short* __restrict__ B,
                                                    void* __restrict__ C,
                                                    const float* __restrict__ bias) {
    __shared__ unsigned short As[64 * 32];    // [m][k]
    __shared__ unsigned short Bs[128 * 32];   // [n][k]

    const int tid = threadIdx.x;
    const int lane = tid & 63;
    const int wave = tid >> 6;
    const int wr = wave >> 1, wc = wave & 1;
    const int row0 = blockIdx.y * 64;
    const int col0 = blockIdx.x * 128;

    const int srow = lane >> 2;
    const int schunk = (lane & 3) * 8;

    f32x4 acc[2][4] = {};

    for (int k0 = 0; k0 < K; k0 += 32) {
        // A: wave stages rows [wave*16, +16); B: [wave*32, +32)
        GLDS16(A + (size_t)(row0 + wave * 16 + srow) * K + k0 + schunk, &As[(wave * 16) * 32]);
        GLDS16(B + (size_t)(col0 + wave * 32 + srow) * K + k0 + schunk, &Bs[(wave * 32) * 32]);
        GLDS16(B + (size_t)(col0 + wave * 32 + 16 + srow) * K + k0 + schunk,
               &Bs[(wave * 32 + 16) * 32]);
        __syncthreads();

        const int kk = (lane >> 4) * 8;
        const int mbase = wr * 32 + (lane & 15);
        const int nbase = wc * 64 + (lane & 15);
        bf16x8 af[2], bf[4];
#pragma unroll
        for (int t = 0; t < 2; ++t) af[t] = *(const bf16x8*)&As[(mbase + t * 16) * 32 + kk];
#pragma unroll
        for (int t = 0; t < 4; ++t) bf[t] = *(const bf16x8*)&Bs[(nbase + t * 16) * 32 + kk];
#pragma unroll
        for (int mt = 0; mt < 2; ++mt)
#pragma unroll
            for (int nt = 0; nt < 4; ++nt)
                acc[mt][nt] = __builtin_amdgcn_mfma_f32_16x16x32_bf16(af[mt], bf[nt],
                                                                      acc[mt][nt], 0, 0, 0);
        __syncthreads();
    }

#pragma unroll
    for (int mt = 0; mt < 2; ++mt) {
        const int grow = row0 + wr * 32 + mt * 16 + (lane >> 4) * 4;
#pragma unroll
        for (int nt = 0; nt < 4; ++nt) {
            const int gcol = col0 + wc * 64 + nt * 16 + (lane & 15);
            const float bv = BIAS ? bias[gcol] : 0.0f;
#pragma unroll
            for (int i = 0; i < 4; ++i) {
                float v = acc[mt][nt][i] + bv;
                if (RELU) v = fmaxf(v, 0.0f);
                const size_t off = (size_t)(grow + i) * N + gcol;
                if (OUT_BF16)
                    ((unsigned short*)C)[off] = f2bf(v);
                else
                    ((float*)C)[off] = v;
            }
        }
    }
}

// ---------------------------------------------------------------------------
// y-GEMM: 64x64 NT bf16, BK=64 + register prefetch + padded LDS, fp32 out+bias.
__global__ __launch_bounds__(256) void gemm64nt_y(int M, int N, int K,
                                                  const unsigned short* __restrict__ A,
                                                  const unsigned short* __restrict__ B,
                                                  float* __restrict__ C,
                                                  const float* __restrict__ bias) {
    __shared__ __align__(16) unsigned short As[64 * LDT];
    __shared__ __align__(16) unsigned short Bs[64 * LDT];
    const int tid = threadIdx.x;
    const int lane = tid & 63;
    const int wave = tid >> 6;
    const int wr = wave >> 1, wc = wave & 1;
    const int row0 = blockIdx.y * 64;
    const int col0 = blockIdx.x * 64;
    const int sr = tid >> 2, sk = (tid & 3) * 16;

    const int niter = K >> 6;
    bf16x8 pa0, pa1, pb0, pb1;
    {
        const unsigned short* ar = A + (size_t)(row0 + sr) * K + sk;
        const unsigned short* br = B + (size_t)(col0 + sr) * K + sk;
        pa0 = *(const bf16x8*)ar; pa1 = *(const bf16x8*)(ar + 8);
        pb0 = *(const bf16x8*)br; pb1 = *(const bf16x8*)(br + 8);
    }

    f32x4 acc[4] = {};
    const int mb = wr * 32 + (lane & 15);
    const int nb = wc * 32 + (lane & 15);

    for (int it = 0; it < niter; ++it) {
        __syncthreads();
        *(bf16x8*)&As[sr * LDT + sk] = pa0; *(bf16x8*)&As[sr * LDT + sk + 8] = pa1;
        *(bf16x8*)&Bs[sr * LDT + sk] = pb0; *(bf16x8*)&Bs[sr * LDT + sk + 8] = pb1;
        __syncthreads();

        {
            const int kn = (it + 1 < niter) ? ((it + 1) << 6) : 0;
            const unsigned short* ar = A + (size_t)(row0 + sr) * K + kn + sk;
            const unsigned short* br = B + (size_t)(col0 + sr) * K + kn + sk;
            pa0 = *(const bf16x8*)ar; pa1 = *(const bf16x8*)(ar + 8);
            pb0 = *(const bf16x8*)br; pb1 = *(const bf16x8*)(br + 8);
        }

#pragma unroll
        for (int kh = 0; kh < 2; ++kh) {
            const int kk = kh * 32 + (lane >> 4) * 8;
            bf16x8 af[2], bf[2];
#pragma unroll
            for (int t = 0; t < 2; ++t) {
                af[t] = *(const bf16x8*)&As[(mb + t * 16) * LDT + kk];
                bf[t] = *(const bf16x8*)&Bs[(nb + t * 16) * LDT + kk];
            }
#pragma unroll
            for (int mt = 0; mt < 2; ++mt)
#pragma unroll
                for (int nt = 0; nt < 2; ++nt)
                    acc[mt * 2 + nt] = __builtin_amdgcn_mfma_f32_16x16x32_bf16(
                        af[mt], bf[nt], acc[mt * 2 + nt], 0, 0, 0);
        }
    }

#pragma unroll
    for (int mt = 0; mt < 2; ++mt) {
        const int grow = row0 + wr * 32 + mt * 16 + (lane >> 4) * 4;
#pragma unroll
        for (int nt = 0; nt < 2; ++nt) {
            const int gcol = col0 + wc * 32 + nt * 16 + (lane & 15);
            const float bv = bias ? bias[gcol] : 0.0f;
#pragma unroll
            for (int i = 0; i < 4; ++i)
                C[(size_t)(grow + i) * N + gcol] = acc[mt * 2 + nt][i] + bv;
        }
    }
}

// ---------------------------------------------------------------------------
extern "C" void kernel_launch(void* const* d_in, const int* in_sizes, int n_in,
                              void* d_out, int out_size, void* d_ws, size_t ws_size,
                              hipStream_t stream) {
    const float* X  = (const float*)d_in[0];  // [B, Dx]
    const float* P  = (const float*)d_in[1];  // [Dz, Dx]
    const float* Am = (const float*)d_in[2];  // [Dz, Dz]
    const float* W1 = (const float*)d_in[3];  // [H, Dz]
    const float* b1 = (const float*)d_in[4];
    const float* W2 = (const float*)d_in[5];  // [H, H]
    const float* b2 = (const float*)d_in[6];
    const float* W3 = (const float*)d_in[7];  // [Dy, H]
    const float* b3 = (const float*)d_in[8];
    float* out = (float*)d_out;               // [B, Dy] fp32

    const size_t S = (size_t)DZ * DZ;  // 262144

    // ---- workspace carve-up (~67 MB) ----
    char* p = (char*)d_ws;
    auto alloc_f = [&](size_t n) { float* r = (float*)p; p += n * 4; return r; };
    auto alloc_h = [&](size_t n) { unsigned short* r = (unsigned short*)p; p += ((n * 2 + 15) & ~15ull); return r; };
    unsigned short* Xb   = alloc_h((size_t)BDIM * DX);
    unsigned short* W2b  = alloc_h((size_t)HD * HD);
    unsigned short* W3b  = alloc_h((size_t)DY * HD);
    unsigned short* W1h  = alloc_h((size_t)HD * DZ);
    unsigned short* W1l  = alloc_h((size_t)HD * DZ);
    unsigned short* Ah   = alloc_h(S);
    unsigned short* Al   = alloc_h(S);
    unsigned short* ATh  = alloc_h(S);
    unsigned short* ATl  = alloc_h(S);
    unsigned short* PTh  = alloc_h(S);
    unsigned short* PTl  = alloc_h(S);
    float* A2f = alloc_f(S);
    float* A3f = alloc_f(S);
    unsigned short* A2h  = alloc_h(S);
    unsigned short* A2l  = alloc_h(S);
    unsigned short* A2Th = alloc_h(S);
    unsigned short* A2Tl = alloc_h(S);
    unsigned short* A4Th = alloc_h(S);
    unsigned short* A4Tl = alloc_h(S);
    float* B0f = alloc_f(S);
    float* B1f = alloc_f(S);
    float* B2f = alloc_f(S);
    unsigned short* B3h  = alloc_h(S);
    unsigned short* B3l  = alloc_h(S);
    unsigned short* H1h  = alloc_h(S);
    unsigned short* H1l  = alloc_h(S);
    unsigned short* H2h  = alloc_h(S);
    unsigned short* H2l  = alloc_h(S);
    unsigned short* H3h  = alloc_h(S);
    unsigned short* H3l  = alloc_h(S);
    unsigned short* RTh  = alloc_h(S);
    unsigned short* RTl  = alloc_h(S);
    unsigned short* C1b  = alloc_h((size_t)HD * DZ);
    unsigned short* h1b  = alloc_h((size_t)BDIM * HD);
    unsigned short* h2b  = alloc_h((size_t)BDIM * HD);

    // ---- L1: converts/splits ----
    CvtJobs J;
    J.src[0] = X;  J.hi[0] = Xb;  J.lo[0] = nullptr; J.n4[0] = BDIM * DX / 4;
    J.src[1] = W2; J.hi[1] = W2b; J.lo[1] = nullptr; J.n4[1] = HD * HD / 4;
    J.src[2] = W3; J.hi[2] = W3b; J.lo[2] = nullptr; J.n4[2] = DY * HD / 4;
    J.src[3] = W1; J.hi[3] = W1h; J.lo[3] = W1l;     J.n4[3] = HD * DZ / 4;
    J.src[4] = Am; J.hi[4] = Ah;  J.lo[4] = Al;      J.n4[4] = (int)(S / 4);
    cvt_multi_k<<<dim3(HD * HD / 4 / 256, 5), 256, 0, stream>>>(J);

    // ---- L2: transposed splits A^T, P^T ----
    split_t_k<<<dim3(DZ / 32, DZ / 32, 2), dim3(32, 8), 0, stream>>>(
        Am, ATh, ATl, P, PTh, PTl, DZ);

    dim3 g8(DZ / 64, DZ / 64);  // 64 blocks

    // ---- L3: A2 = A@A -> f32 + split + splitT ----
    {
        G64In i{Ah, Al, ATh, ATl, nullptr};
        G64Out o{A2f, A2h, A2l, A2Th, A2Tl};
        g64_one<<<g8, 256, 0, stream>>>(i, o, DZ, DZ, DZ);
    }
    // ---- L4: dual {A3 = A2@A -> f32 ; A4 = A2@A2 -> splitT} ----
    {
        G64In i0{A2h, A2l, ATh, ATl, nullptr};
        G64Out o0{A3f, nullptr, nullptr, nullptr, nullptr};
        G64In i1{A2h, A2l, A2Th, A2Tl, nullptr};
        G64Out o1{nullptr, nullptr, nullptr, A4Th, A4Tl};
        g64_dual<<<dim3(DZ / 64, DZ / 64, 2), 256, 0, stream>>>(i0, o0, i1, o1, DZ, DZ, DZ);
    }
    // ---- L5: PS groups B0..B3 ----
    e0_k<<<dim3((int)(S / 4 / 256)), 256, 0, stream>>>(Am, A2f, A3f, B0f, B1f, B2f, B3h, B3l);

    // ---- L6..L8: Horner  H = ((B3*A4 + B2)*A4 + B1)*A4 + B0 ----
    {
        G64In i{B3h, B3l, A4Th, A4Tl, B2f};
        G64Out o{nullptr, H1h, H1l, nullptr, nullptr};
        g64_one<<<g8, 256, 0, stream>>>(i, o, DZ, DZ, DZ);
    }
    {
        G64In i{H1h, H1l, A4Th, A4Tl, B1f};
        G64Out o{nullptr, H2h, H2l, nullptr, nullptr};
        g64_one<<<g8, 256, 0, stream>>>(i, o, DZ, DZ, DZ);
    }
    {
        G64In i{H2h, H2l, A4Th, A4Tl, B0f};
        G64Out o{nullptr, H3h, H3l, nullptr, nullptr};
        g64_one<<<g8, 256, 0, stream>>>(i, o, DZ, DZ, DZ);
    }
    // ---- L9: R = H3@P -> R^T split ----
    {
        G64In i{H3h, H3l, PTh, PTl, nullptr};
        G64Out o{nullptr, nullptr, nullptr, RTh, RTl};
        g64_one<<<g8, 256, 0, stream>>>(i, o, DZ, DZ, DZ);
    }
    // ---- L10: C1 = W1@R -> bf16 hi [H, Dx] ----
    {
        G64In i{W1h, W1l, RTh, RTl, nullptr};
        G64Out o{nullptr, C1b, nullptr, nullptr, nullptr};
        g64_one<<<dim3(DZ / 64, HD / 64), 256, 0, stream>>>(i, o, HD, DZ, DZ);
    }

    // ---- L11: h1 = relu(X @ C1^T + b1)  [B,H], K=Dx — 64x128 tile, 1024 blocks
    gemm_bf16_v2<1, 1, 1><<<dim3(HD / 128, BDIM / 64), 256, 0, stream>>>(
        BDIM, HD, DX, Xb, C1b, h1b, b1);
    // ---- L12: h2 = relu(h1 @ W2^T + b2) [B,H]
    gemm_bf16_v2<1, 1, 1><<<dim3(HD / 128, BDIM / 64), 256, 0, stream>>>(
        BDIM, HD, HD, h1b, W2b, h2b, b2);
    // ---- L13: y = h2 @ W3^T + b3 (fp32 out)
    gemm64nt_y<<<dim3(DY / 64, BDIM / 64), 256, 0, stream>>>(
        BDIM, DY, HD, h2b, W3b, out, b3);
}